// Round 17
// baseline (188.999 us; speedup 1.0000x reference)
//
#include <hip/hip_runtime.h>
#include <stdint.h>

#define B_   2
#define L_   2048
#define DM   2048
#define NH   32
#define NKV  8
#define HD   64

typedef __attribute__((ext_vector_type(8))) short short8;
typedef __attribute__((ext_vector_type(4))) float f32x4;
typedef __attribute__((ext_vector_type(16))) float f32x16;

__device__ __forceinline__ unsigned short f2b(float f) {
  union { float f; unsigned int u; } x; x.f = f;
  unsigned int u = x.u + 0x7fffu + ((x.u >> 16) & 1u);
  return (unsigned short)(u >> 16);
}

__device__ __forceinline__ void gload16(const void* g, void* l) {
  __builtin_amdgcn_global_load_lds((const __attribute__((address_space(1))) void*)(g),
                                   (__attribute__((address_space(3))) void*)(l), 16, 0, 0);
}

__device__ __forceinline__ unsigned int cvtpk_bf16(float a, float b) {
  unsigned int r;
  asm("v_cvt_pk_bf16_f32 %0, %1, %2" : "=v"(r) : "v"(a), "v"(b));
  return r;
}

__device__ __forceinline__ void pl32swap(unsigned int& a, unsigned int& b) {
  asm("v_permlane32_swap_b32 %0, %1" : "+v"(a), "+v"(b));
}

#if __has_builtin(__builtin_amdgcn_exp2f)
__device__ __forceinline__ float fexp2(float x) { return __builtin_amdgcn_exp2f(x); }
#else
__device__ __forceinline__ float fexp2(float x) {
  float r; asm("v_exp_f32 %0, %1" : "=v"(r) : "v"(x)); return r;
}
#endif

union U8 { unsigned int u[4]; short8 s; };

// ---------------- weights-only f32 -> bf16 convert (Wq, Wk, Wv, Wo) ----------------
__global__ void conv_all(const float* __restrict__ Wq, const float* __restrict__ Wk,
                         const float* __restrict__ Wv, const float* __restrict__ Wo,
                         unsigned short* __restrict__ wqkv, unsigned short* __restrict__ wo) {
  int u = blockIdx.x * blockDim.x + threadIdx.x;
  const float* s;
  unsigned short* d;
  if (u < 1048576)       { s = Wq + (size_t)u * 4;             d = wqkv + (size_t)u * 4; }
  else if (u < 1310720)  { s = Wk + (size_t)(u - 1048576) * 4; d = wqkv + 4194304 + (size_t)(u - 1048576) * 4; }
  else if (u < 1572864)  { s = Wv + (size_t)(u - 1310720) * 4; d = wqkv + 5242880 + (size_t)(u - 1310720) * 4; }
  else                   { s = Wo + (size_t)(u - 1572864) * 4; d = wo + (size_t)(u - 1572864) * 4; }
  float4 v = *(const float4*)s;
  ushort4 o;
  o.x = f2b(v.x); o.y = f2b(v.y); o.z = f2b(v.z); o.w = f2b(v.w);
  *(ushort4*)d = o;
}

// ======== gemm_bt staging (256 threads): 128x32 A + 128x32 B (both bf16), chunk-swizzled ====
#define GSTAGE4(SM, BUF, K0)                                                    \
  {                                                                             \
    unsigned short* Ad = (SM) + (BUF) * 8192;                                   \
    gload16(Ab + (size_t)srow * K + (K0) + scolz,        Ad + w * 512);         \
    gload16(Ab + (size_t)(srow + 64) * K + (K0) + scolz, Ad + 2048 + w * 512);  \
    gload16(Bb + (size_t)srow * K + (K0) + scolz,        Ad + 4096 + w * 512);  \
    gload16(Bb + (size_t)(srow + 64) * K + (K0) + scolz, Ad + 6144 + w * 512);  \
  }

// ---------------- GEMM: C(MxN,f32) = A(MxK,bf16) * B(NxK,bf16)^T (for Wo) ----------------
__global__ __launch_bounds__(256) void gemm_bt(const unsigned short* __restrict__ A,
                                               const unsigned short* __restrict__ Bw,
                                               float* __restrict__ C,
                                               int M, int N, int K) {
  __shared__ unsigned short sm[3 * 8192];
  const int tid = threadIdx.x;
  const int w = tid >> 6, l = tid & 63;
  const int lo = l & 15, hi = l >> 4;
  const int xcd = blockIdx.x & 7;
  const int wi = blockIdx.x >> 3;
  const int bm = (xcd >> 1) * 8 + (wi >> 3);
  const int bn = (xcd & 1) * 8 + (wi & 7);
  const int wm = w >> 1, wn = w & 1;
  f32x4 acc[4][4] = {};
  const unsigned short* Ab = A + (size_t)(bm * 128) * K;
  const unsigned short* Bb = Bw + (size_t)(bn * 128) * K;
  const int srow = tid >> 2;
  const int scolz = (((tid & 3) ^ ((tid >> 2) & 3)) * 8);
  const int csw = lo & 3;

  const int nk = K >> 5;
  GSTAGE4(sm, 0, 0);
  GSTAGE4(sm, 1, 32);
  int cur = 0;
  for (int t = 0; t < nk; ++t) {
    if (t + 1 < nk) asm volatile("s_waitcnt vmcnt(4)" ::: "memory");
    else            asm volatile("s_waitcnt vmcnt(0)" ::: "memory");
    __builtin_amdgcn_s_barrier();
    __builtin_amdgcn_sched_barrier(0);
    const int nb2 = (cur + 2 >= 3) ? cur - 1 : cur + 2;
    if (t + 2 < nk) GSTAGE4(sm, nb2, (t + 2) * 32);
    const unsigned short* As = sm + cur * 8192;
    const unsigned short* Bs = As + 4096;
    const int kk = (hi ^ csw) * 8;
    short8 a[4], b[4];
#pragma unroll
    for (int i = 0; i < 4; ++i)
      a[i] = *(const short8*)&As[(wm * 64 + i * 16 + lo) * 32 + kk];
#pragma unroll
    for (int j = 0; j < 4; ++j)
      b[j] = *(const short8*)&Bs[(wn * 64 + j * 16 + lo) * 32 + kk];
    __builtin_amdgcn_s_setprio(1);
#pragma unroll
    for (int i = 0; i < 4; ++i)
#pragma unroll
      for (int j = 0; j < 4; ++j)
        acc[i][j] = __builtin_amdgcn_mfma_f32_16x16x32_bf16(a[i], b[j], acc[i][j], 0, 0, 0);
    __builtin_amdgcn_s_setprio(0);
    cur = (cur + 1 >= 3) ? 0 : cur + 1;
  }
  const int r0 = hi * 4;
#pragma unroll
  for (int i = 0; i < 4; ++i)
#pragma unroll
    for (int j = 0; j < 4; ++j)
#pragma unroll
      for (int r = 0; r < 4; ++r)
        C[(size_t)(bm * 128 + wm * 64 + i * 16 + r0 + r) * N + bn * 128 + wn * 64 + j * 16 + lo] =
            acc[i][j][r];
}

// ======== gemm_qkv staging (512 threads): A f32 128x32 (16KB) + B bf16 128x32 (8KB) ========
// Buffer = 24KB (12288 shorts): A-f32 [0,8192), B [8192,12288) in short units.
// A rows = 128B = 8 chunks, src col pre-swizzled by (row&7); B as r14 (4-chunk swizzle).
#define GSTAGEQ(SM, BUF, K0)                                                       \
  {                                                                                \
    unsigned short* Ad = (SM) + (BUF) * 12288;                                     \
    gload16(Af + (size_t)(aRow)*2048 + (K0) + acol,        Ad + w * 512);          \
    gload16(Af + (size_t)(aRow + 64)*2048 + (K0) + acol,   Ad + 4096 + w * 512);   \
    gload16(Bb + (size_t)srow * 2048 + (K0) + scolz,       Ad + 8192 + w * 512);   \
  }

// ---------------- QKV GEMM, A read直接 from x (f32), fused RoPE / V-transpose --------------
// grid 768 (32 bm x 24 bn), 512 threads = 8 waves (4m x 2n, wave tile 32x64); XCD tile 8x12.
// 3-buffer rotating pipeline, vmcnt(3) (3 loads/tile/thread). LDS 72KB -> 2 blocks/CU.
__global__ __launch_bounds__(512) void gemm_qkv(const float* __restrict__ X,
                                                const unsigned short* __restrict__ Bw,
                                                const float* __restrict__ cosT,
                                                const float* __restrict__ sinT,
                                                unsigned short* __restrict__ qrope,
                                                unsigned short* __restrict__ krope,
                                                unsigned short* __restrict__ vt) {
  const int K = 2048;
  __shared__ unsigned short sm[3 * 12288];     // 72 KB
  const int tid = threadIdx.x;
  const int w = tid >> 6, l = tid & 63;
  const int lo = l & 15, hi = l >> 4;
  const int xcd = blockIdx.x & 7;
  const int wi = blockIdx.x >> 3;
  const int bm = (xcd >> 1) * 8 + wi / 12;
  const int bn = (xcd & 1) * 12 + wi % 12;
  const int wm = w >> 1, wn = w & 1;
  f32x4 acc[2][4] = {};
  const float* Af = X + (size_t)(bm * 128) * K;
  const unsigned short* Bb = Bw + (size_t)(bn * 128) * K;
  // A staging: per-wave rows w*8+(l>>3) (+64 for 2nd gload); col swizzled by (row&7)
  const int aRow = w * 8 + (l >> 3);
  const int acol = ((l & 7) ^ ((l >> 3) & 7)) * 4;        // floats
  // B staging: r14 pattern
  const int srow = tid >> 2;
  const int scolz = (((tid & 3) ^ ((tid >> 2) & 3)) * 8); // shorts
  const int csw = lo & 3;                                  // B read-side XOR
  const int aswr = lo & 7;                                 // A read-side XOR (row&7)

  const int nk = K >> 5;
  GSTAGEQ(sm, 0, 0);
  GSTAGEQ(sm, 1, 32);
  int cur = 0;
  for (int t = 0; t < nk; ++t) {
    if (t + 1 < nk) asm volatile("s_waitcnt vmcnt(3)" ::: "memory");
    else            asm volatile("s_waitcnt vmcnt(0)" ::: "memory");
    __builtin_amdgcn_s_barrier();
    __builtin_amdgcn_sched_barrier(0);
    const int nb2 = (cur + 2 >= 3) ? cur - 1 : cur + 2;
    if (t + 2 < nk) GSTAGEQ(sm, nb2, (t + 2) * 32);
    const float* Asf = (const float*)(sm + cur * 12288);
    const unsigned short* Bs = sm + cur * 12288 + 8192;
    short8 a[2], b[4];
#pragma unroll
    for (int i = 0; i < 2; ++i) {
      const int rowA = wm * 32 + i * 16 + lo;
      f32x4 f0 = *(const f32x4*)(Asf + rowA * 32 + (((2 * hi) ^ aswr) << 2));
      f32x4 f1 = *(const f32x4*)(Asf + rowA * 32 + (((2 * hi + 1) ^ aswr) << 2));
      U8 ua;
      ua.u[0] = cvtpk_bf16(f0[0], f0[1]);
      ua.u[1] = cvtpk_bf16(f0[2], f0[3]);
      ua.u[2] = cvtpk_bf16(f1[0], f1[1]);
      ua.u[3] = cvtpk_bf16(f1[2], f1[3]);
      a[i] = ua.s;
    }
    const int kk = (hi ^ csw) * 8;
#pragma unroll
    for (int j = 0; j < 4; ++j)
      b[j] = *(const short8*)&Bs[(wn * 64 + j * 16 + lo) * 32 + kk];
    __builtin_amdgcn_s_setprio(1);
#pragma unroll
    for (int i = 0; i < 2; ++i)
#pragma unroll
      for (int j = 0; j < 4; ++j)
        acc[i][j] = __builtin_amdgcn_mfma_f32_16x16x32_bf16(a[i], b[j], acc[i][j], 0, 0, 0);
    __builtin_amdgcn_s_setprio(0);
    cur = (cur + 1 >= 3) ? 0 : cur + 1;
  }

  // ---- epilogue: RoPE/copy into LDS tile [128][132] bf16, then coalesced stores ----
  __syncthreads();
  unsigned short* T = sm;
  const float SC = 0.18033688011112042f; // 0.125 * log2(e), folded into Q
  if (bn < 16) {
#pragma unroll
    for (int i = 0; i < 2; ++i)
#pragma unroll
      for (int r = 0; r < 4; ++r) {
        const int tr = wm * 32 + i * 16 + hi * 4 + r;
        const int lpos = (bm * 128 + tr) & (L_ - 1);
        const float* cr = cosT + lpos * 64;
        const float* sr = sinT + lpos * 64;
        float q0 = acc[i][0][r], q1 = acc[i][1][r], q2 = acc[i][2][r], q3 = acc[i][3][r];
        unsigned short* tp = T + tr * 132 + wn * 64 + lo;
        tp[0]  = f2b((q0 * cr[lo]      - q2 * sr[lo])      * SC);
        tp[16] = f2b((q1 * cr[lo + 16] - q3 * sr[lo + 16]) * SC);
        tp[32] = f2b((q2 * cr[lo + 32] + q0 * sr[lo + 32]) * SC);
        tp[48] = f2b((q3 * cr[lo + 48] + q1 * sr[lo + 48]) * SC);
      }
  } else if (bn < 20) {
#pragma unroll
    for (int i = 0; i < 2; ++i)
#pragma unroll
      for (int r = 0; r < 4; ++r) {
        const int tr = wm * 32 + i * 16 + hi * 4 + r;
        const int lpos = (bm * 128 + tr) & (L_ - 1);
        const float* cr = cosT + lpos * 64;
        const float* sr = sinT + lpos * 64;
        float q0 = acc[i][0][r], q1 = acc[i][1][r], q2 = acc[i][2][r], q3 = acc[i][3][r];
        unsigned short* tp = T + tr * 132 + wn * 64 + lo;
        tp[0]  = f2b(q0 * cr[lo]      - q2 * sr[lo]);
        tp[16] = f2b(q1 * cr[lo + 16] - q3 * sr[lo + 16]);
        tp[32] = f2b(q2 * cr[lo + 32] + q0 * sr[lo + 32]);
        tp[48] = f2b(q3 * cr[lo + 48] + q1 * sr[lo + 48]);
      }
  } else {
#pragma unroll
    for (int i = 0; i < 2; ++i)
#pragma unroll
      for (int r = 0; r < 4; ++r) {
        const int tr = wm * 32 + i * 16 + hi * 4 + r;
        unsigned short* tp = T + tr * 132 + wn * 64 + lo;
#pragma unroll
        for (int j = 0; j < 4; ++j)
          tp[j * 16] = f2b(acc[i][j][r]);
      }
  }
  __syncthreads();

  const int bb = bm >> 4;
  const int lp0 = (bm & 15) * 128;
  if (bn < 20) {
    unsigned short* base = (bn < 16) ? qrope : krope;
    const int nheads = (bn < 16) ? NH : NKV;
    const int h0 = (bn < 16) ? bn * 2 : (bn - 16) * 2;
#pragma unroll
    for (int it = 0; it < 4; ++it) {
      const int tr2 = it * 32 + (tid >> 4);
      const int c = (tid & 15) * 8;
      short8 v = *(const short8*)(T + tr2 * 132 + c);
      const int hl = c >> 6, d8 = c & 63;
      *(short8*)(base + ((size_t)(bb * nheads + h0 + hl) * L_ + lp0 + tr2) * 64 + d8) = v;
    }
  } else {
    const int g0 = (bn - 20) * 2;
#pragma unroll
    for (int it = 0; it < 4; ++it) {
      const int dl = it * 32 + (tid >> 4);
      const int ch = (tid & 15) * 8;
      U8 v;
#pragma unroll
      for (int k2 = 0; k2 < 4; ++k2) {
        unsigned short e0 = T[(ch + 2 * k2) * 132 + dl];
        unsigned short e1 = T[(ch + 2 * k2 + 1) * 132 + dl];
        v.u[k2] = (unsigned int)e0 | ((unsigned int)e1 << 16);
      }
      const int gl = dl >> 6, d = dl & 63;
      *(short8*)(vt + ((size_t)((bb * NKV + g0 + gl) * HD + d)) * L_ + lp0 + ch) = v.s;
    }
  }
}

// ---------------- Flash attention (causal, GQA), 32x32x16 swapped-operand ----------------
// (r11 verbatim — known good)
__global__ __launch_bounds__(256) void attn(const unsigned short* __restrict__ Qb,
                                            const unsigned short* __restrict__ Kb,
                                            const unsigned short* __restrict__ Vtb,
                                            unsigned short* __restrict__ AO) {
  __shared__ unsigned short smem[3 * 8192];
  const int h = blockIdx.y, b = blockIdx.z;
  const int g = h >> 2;
  const int tid = threadIdx.x;
  const int w = tid >> 6, l = tid & 63;
  const int q5 = l & 31, hi2 = l >> 5;

  const unsigned short* Qh = Qb + (size_t)(b * NH + h) * L_ * HD;
  const char* Kg = (const char*)(Kb + (size_t)(b * NKV + g) * L_ * HD);
  const char* Vg = (const char*)(Vtb + (size_t)(b * NKV + g) * HD * L_);

  const int r8 = l >> 3;
  const int swz_src = ((l & 7) ^ r8) * 16;
  const int myswz = (q5 & 7) << 4;

  const int koff0 = (w * 16 + r8) * 128 + swz_src;
  const int koff1 = koff0 + 1024;
  const int voff0 = (w * 16 + r8) * 4096 + swz_src;
  const int voff1 = voff0 + 32768;
  const int dA0 = w * 1024;
  const int dA1 = dA0 + 512;

  int cA[4];
#pragma unroll
  for (int sc = 0; sc < 4; ++sc) cA[sc] = (sc * 32 + hi2 * 16) ^ myswz;
  const int rK = q5 * 128;

  short8 av2c;
#pragma unroll
  for (int j = 0; j < 8; ++j) av2c[j] = (q5 == 0) ? (short)0x3F80 : (short)0;

#define STAGE2(BUF)                                            \
  {                                                            \
    unsigned short* Kd = smem + (BUF) * 8192;                  \
    gload16(kgp + koff0, Kd + dA0);                            \
    gload16(kgp + koff1, Kd + dA1);                            \
    gload16(vgp + voff0, Kd + 4096 + dA0);                     \
    gload16(vgp + voff1, Kd + 4096 + dA1);                     \
  }

  for (int pass = 0; pass < 2; ++pass) {
    const int qb = pass ? 15 - blockIdx.x : blockIdx.x;
    const unsigned short* Qp = Qh + (size_t)(qb * 128) * HD;

    short8 bq[4];
#pragma unroll
    for (int sc = 0; sc < 4; ++sc)
      bq[sc] = *(const short8*)(Qp + (w * 32 + q5) * HD + sc * 16 + hi2 * 8);

    f32x16 o0 = {}, o1 = {}, o2 = {};
    const int qg = qb * 128 + w * 32 + q5;

    const char* kgp = Kg;
    const char* vgp = Vg;

    const int nt = 2 * qb + 2;
    STAGE2(0);
    kgp += 8192; vgp += 128;
    int cur = 0;
    for (int kt = 0; kt < nt; ++kt) {
      const int nb = (cur == 2) ? 0 : cur + 1;
      if (kt + 1 < nt) {
        STAGE2(nb);
        kgp += 8192; vgp += 128;
        asm volatile("s_waitcnt vmcnt(4)" ::: "memory");
      } else {
        asm volatile("s_waitcnt vmcnt(0)" ::: "memory");
      }
      __builtin_amdgcn_s_barrier();
      __builtin_amdgcn_sched_barrier(0);

      const char* kb = (const char*)smem + cur * 16384 + rK;
      const bool active = (kt * 64 <= qb * 128 + w * 32 + 31);
      if (active) {
        f32x16 s0 = {}, s1 = {};
        __builtin_amdgcn_s_setprio(1);
#pragma unroll
        for (int sc = 0; sc < 4; ++sc) {
          short8 ak = *(const short8*)(kb + cA[sc]);
          s0 = __builtin_amdgcn_mfma_f32_32x32x16_bf16(ak, bq[sc], s0, 0, 0, 0);
        }
#pragma unroll
        for (int sc = 0; sc < 4; ++sc) {
          short8 ak = *(const short8*)(kb + 4096 + cA[sc]);
          s1 = __builtin_amdgcn_mfma_f32_32x32x16_bf16(ak, bq[sc], s1, 0, 0, 0);
        }
        __builtin_amdgcn_s_setprio(0);
        if (kt >= 2 * qb) {
#pragma unroll
          for (int r = 0; r < 16; ++r) {
            const int krow = (r & 3) + 8 * (r >> 2) + 4 * hi2;
            if (kt * 64 + krow > qg)      s0[r] = -1e30f;
            if (kt * 64 + 32 + krow > qg) s1[r] = -1e30f;
          }
        }
#pragma unroll
        for (int r = 0; r < 16; ++r) s0[r] = fexp2(s0[r]);
#pragma unroll
        for (int r = 0; r < 16; ++r) s1[r] = fexp2(s1[r]);
        unsigned int pa[4][4];
#define PACK8(S, Bq, OUT)                                        \
        {                                                        \
          unsigned int u0 = cvtpk_bf16(S[Bq + 0], S[Bq + 1]);    \
          unsigned int u1 = cvtpk_bf16(S[Bq + 2], S[Bq + 3]);    \
          unsigned int u2 = cvtpk_bf16(S[Bq + 4], S[Bq + 5]);    \
          unsigned int u3 = cvtpk_bf16(S[Bq + 6], S[Bq + 7]);    \
          pl32swap(u0, u2); pl32swap(u1, u3);                    \
          OUT[0] = u0; OUT[1] = u1; OUT[2] = u2; OUT[3] = u3;    \
        }
        PACK8(s0, 0, pa[0]); PACK8(s0, 8, pa[1]);
        PACK8(s1, 0, pa[2]); PACK8(s1, 8, pa[3]);
#undef PACK8
        __builtin_amdgcn_s_setprio(1);
#pragma unroll
        for (int kc = 0; kc < 4; ++kc) {
          U8 p; p.u[0] = pa[kc][0]; p.u[1] = pa[kc][1]; p.u[2] = pa[kc][2]; p.u[3] = pa[kc][3];
          short8 av0 = *(const short8*)(kb + 8192 + cA[kc]);
          o0 = __builtin_amdgcn_mfma_f32_32x32x16_bf16(av0, p.s, o0, 0, 0, 0);
          short8 av1 = *(const short8*)(kb + 12288 + cA[kc]);
          o1 = __builtin_amdgcn_mfma_f32_32x32x16_bf16(av1, p.s, o1, 0, 0, 0);
          o2 = __builtin_amdgcn_mfma_f32_32x32x16_bf16(av2c, p.s, o2, 0, 0, 0);
        }
        __builtin_amdgcn_s_setprio(0);
      }
      cur = nb;
    }

    __builtin_amdgcn_s_barrier();

    const float ls = o2[0] + __shfl_xor(o2[0], 32);
    const float inv = 1.f / ls;
    o0 *= inv;
    o1 *= inv;
    const int qrow = w * 32 + q5;
#pragma unroll
    for (int df = 0; df < 2; ++df) {
      const f32x16& o = df ? o1 : o0;
#pragma unroll
      for (int gq = 0; gq < 4; ++gq) {
        unsigned int ulo = cvtpk_bf16(o[4 * gq + 0], o[4 * gq + 1]);
        unsigned int uhi = cvtpk_bf16(o[4 * gq + 2], o[4 * gq + 3]);
        const int colb = df * 64 + gq * 16 + hi2 * 8;
        *(unsigned long long*)((char*)smem + qrow * 128 + (colb ^ myswz)) =
            ((unsigned long long)uhi << 32) | (unsigned long long)ulo;
      }
    }
    __syncthreads();
#pragma unroll
    for (int it = 0; it < 4; ++it) {
      const int row = it * 32 + (tid >> 3);
      const int colb = (tid & 7) * 16;
      short8 v = *(const short8*)((const char*)smem + row * 128 + (colb ^ ((row & 7) << 4)));
      *(short8*)((char*)AO + ((size_t)(b * L_ + qb * 128 + row) * 2048 + h * 64) * 2 + colb) = v;
    }
    __syncthreads();
  }
#undef STAGE2
}

extern "C" void kernel_launch(void* const* d_in, const int* in_sizes, int n_in,
                              void* d_out, int out_size, void* d_ws, size_t ws_size,
                              hipStream_t stream) {
  const float* x    = (const float*)d_in[0];
  const float* cosT = (const float*)d_in[1];
  const float* sinT = (const float*)d_in[2];
  const float* Wq   = (const float*)d_in[3];
  const float* Wk   = (const float*)d_in[4];
  const float* Wv   = (const float*)d_in[5];
  const float* Wo   = (const float*)d_in[6];
  float* out = (float*)d_out;

  char* ws = (char*)d_ws;
  unsigned short* wqkv  = (unsigned short*)ws;        // 6,291,456 el (Wq | Wk | Wv)
  unsigned short* wo    = wqkv + 6291456;             // 4,194,304 el
  unsigned short* qrope = wo + 4194304;               // 8,388,608 el  (B,NH,L,64) roped*SC
  unsigned short* krope = qrope + 8388608;            // 2,097,152 el  (B,NKV,L,64) roped
  unsigned short* vt    = krope + 2097152;            // 2,097,152 el  (B,NKV,64,L)
  unsigned short* ao    = vt + 2097152;               // 8,388,608 el  (B,L,2048)

  conv_all<<<10240, 256, 0, stream>>>(Wq, Wk, Wv, Wo, wqkv, wo);

  gemm_qkv<<<768, 512, 0, stream>>>(x, wqkv, cosT, sinT, qrope, krope, vt);

  attn<<<dim3(8, 32, 2), 256, 0, stream>>>(qrope, krope, vt, ao);

  gemm_bt<<<512, 256, 0, stream>>>(ao, wo, out, 4096, 2048, 2048);
}

// Round 18
// 179.106 us; speedup vs baseline: 1.0552x; 1.0552x over previous
//
#include <hip/hip_runtime.h>
#include <stdint.h>

#define B_   2
#define L_   2048
#define DM   2048
#define NH   32
#define NKV  8
#define HD   64

typedef __attribute__((ext_vector_type(8))) short short8;
typedef __attribute__((ext_vector_type(4))) float f32x4;
typedef __attribute__((ext_vector_type(16))) float f32x16;

__device__ __forceinline__ unsigned short f2b(float f) {
  union { float f; unsigned int u; } x; x.f = f;
  unsigned int u = x.u + 0x7fffu + ((x.u >> 16) & 1u);
  return (unsigned short)(u >> 16);
}

__device__ __forceinline__ void gload16(const void* g, void* l) {
  __builtin_amdgcn_global_load_lds((const __attribute__((address_space(1))) void*)(g),
                                   (__attribute__((address_space(3))) void*)(l), 16, 0, 0);
}

__device__ __forceinline__ unsigned int cvtpk_bf16(float a, float b) {
  unsigned int r;
  asm("v_cvt_pk_bf16_f32 %0, %1, %2" : "=v"(r) : "v"(a), "v"(b));
  return r;
}

__device__ __forceinline__ void pl32swap(unsigned int& a, unsigned int& b) {
  asm("v_permlane32_swap_b32 %0, %1" : "+v"(a), "+v"(b));
}

#if __has_builtin(__builtin_amdgcn_exp2f)
__device__ __forceinline__ float fexp2(float x) { return __builtin_amdgcn_exp2f(x); }
#else
__device__ __forceinline__ float fexp2(float x) {
  float r; asm("v_exp_f32 %0, %1" : "=v"(r) : "v"(x)); return r;
}
#endif

union U8 { unsigned int u[4]; short8 s; };

// ---------------- merged f32 -> bf16 convert (x, Wq, Wk, Wv, Wo) ----------------
__global__ void conv_all(const float* __restrict__ x,  const float* __restrict__ Wq,
                         const float* __restrict__ Wk, const float* __restrict__ Wv,
                         const float* __restrict__ Wo,
                         unsigned short* __restrict__ xb, unsigned short* __restrict__ wqkv,
                         unsigned short* __restrict__ wo) {
  int u = blockIdx.x * blockDim.x + threadIdx.x;
  const float* s;
  unsigned short* d;
  if (u < 2097152)            { s = x  + (size_t)u * 4;               d = xb + (size_t)u * 4; }
  else if (u < 3145728)       { s = Wq + (size_t)(u - 2097152) * 4;   d = wqkv + (size_t)(u - 2097152) * 4; }
  else if (u < 3407872)       { s = Wk + (size_t)(u - 3145728) * 4;   d = wqkv + 4194304 + (size_t)(u - 3145728) * 4; }
  else if (u < 3670016)       { s = Wv + (size_t)(u - 3407872) * 4;   d = wqkv + 5242880 + (size_t)(u - 3407872) * 4; }
  else                        { s = Wo + (size_t)(u - 3670016) * 4;   d = wo + (size_t)(u - 3670016) * 4; }
  float4 v = *(const float4*)s;
  ushort4 o;
  o.x = f2b(v.x); o.y = f2b(v.y); o.z = f2b(v.z); o.w = f2b(v.w);
  *(ushort4*)d = o;
}

// ======== gemm_bt staging (256 threads): 128x32 A + 128x32 B, chunk-swizzled ========
#define GSTAGE4(SM, BUF, K0)                                                    \
  {                                                                             \
    unsigned short* Ad = (SM) + (BUF) * 8192;                                   \
    gload16(Ab + (size_t)srow * K + (K0) + scolz,        Ad + w * 512);         \
    gload16(Ab + (size_t)(srow + 64) * K + (K0) + scolz, Ad + 2048 + w * 512);  \
    gload16(Bb + (size_t)srow * K + (K0) + scolz,        Ad + 4096 + w * 512);  \
    gload16(Bb + (size_t)(srow + 64) * K + (K0) + scolz, Ad + 6144 + w * 512);  \
  }

// ---------------- GEMM: C(MxN,f32) = A(MxK,bf16) * B(NxK,bf16)^T (for Wo) ----------------
// 256 threads, 4 waves (2x2, wave tile 64x64); grid 512; XCD tile 8x8.
__global__ __launch_bounds__(256) void gemm_bt(const unsigned short* __restrict__ A,
                                               const unsigned short* __restrict__ Bw,
                                               float* __restrict__ C,
                                               int M, int N, int K) {
  __shared__ unsigned short sm[3 * 8192];
  const int tid = threadIdx.x;
  const int w = tid >> 6, l = tid & 63;
  const int lo = l & 15, hi = l >> 4;
  const int xcd = blockIdx.x & 7;
  const int wi = blockIdx.x >> 3;
  const int bm = (xcd >> 1) * 8 + (wi >> 3);
  const int bn = (xcd & 1) * 8 + (wi & 7);
  const int wm = w >> 1, wn = w & 1;
  f32x4 acc[4][4] = {};
  const unsigned short* Ab = A + (size_t)(bm * 128) * K;
  const unsigned short* Bb = Bw + (size_t)(bn * 128) * K;
  const int srow = tid >> 2;
  const int scolz = (((tid & 3) ^ ((tid >> 2) & 3)) * 8);
  const int csw = lo & 3;

  const int nk = K >> 5;
  GSTAGE4(sm, 0, 0);
  GSTAGE4(sm, 1, 32);
  int cur = 0;
  for (int t = 0; t < nk; ++t) {
    if (t + 1 < nk) asm volatile("s_waitcnt vmcnt(4)" ::: "memory");
    else            asm volatile("s_waitcnt vmcnt(0)" ::: "memory");
    __builtin_amdgcn_s_barrier();
    __builtin_amdgcn_sched_barrier(0);
    const int nb2 = (cur + 2 >= 3) ? cur - 1 : cur + 2;
    if (t + 2 < nk) GSTAGE4(sm, nb2, (t + 2) * 32);
    const unsigned short* As = sm + cur * 8192;
    const unsigned short* Bs = As + 4096;
    const int kk = (hi ^ csw) * 8;
    short8 a[4], b[4];
#pragma unroll
    for (int i = 0; i < 4; ++i)
      a[i] = *(const short8*)&As[(wm * 64 + i * 16 + lo) * 32 + kk];
#pragma unroll
    for (int j = 0; j < 4; ++j)
      b[j] = *(const short8*)&Bs[(wn * 64 + j * 16 + lo) * 32 + kk];
    __builtin_amdgcn_s_setprio(1);
#pragma unroll
    for (int i = 0; i < 4; ++i)
#pragma unroll
      for (int j = 0; j < 4; ++j)
        acc[i][j] = __builtin_amdgcn_mfma_f32_16x16x32_bf16(a[i], b[j], acc[i][j], 0, 0, 0);
    __builtin_amdgcn_s_setprio(0);
    cur = (cur + 1 >= 3) ? 0 : cur + 1;
  }
  const int r0 = hi * 4;
#pragma unroll
  for (int i = 0; i < 4; ++i)
#pragma unroll
    for (int j = 0; j < 4; ++j)
#pragma unroll
      for (int r = 0; r < 4; ++r)
        C[(size_t)(bm * 128 + wm * 64 + i * 16 + r0 + r) * N + bn * 128 + wn * 64 + j * 16 + lo] =
            acc[i][j][r];
}

// ======== gemm_qkv staging (512 threads): 256x32 A + 256x32 B, chunk-swizzled ========
#define GSTAGEQ(SM, BUF, K0)                                                      \
  {                                                                               \
    unsigned short* Ad = (SM) + (BUF) * 16384;                                    \
    gload16(Ab + (size_t)srow * K + (K0) + scolz,         Ad + w * 512);          \
    gload16(Ab + (size_t)(srow + 128) * K + (K0) + scolz, Ad + 4096 + w * 512);   \
    gload16(Bb + (size_t)srow * K + (K0) + scolz,         Ad + 8192 + w * 512);   \
    gload16(Bb + (size_t)(srow + 128) * K + (K0) + scolz, Ad + 12288 + w * 512);  \
  }

// ---------------- QKV GEMM, 256x256 tile, fused RoPE / V-transpose epilogue ----------------
// grid 192 (16 bm x 12 bn), 512 threads = 8 waves (2M x 4N, wave tile 128x64).
// 3-buffer rotating pipeline, vmcnt(4); LDS 96KB -> 1 block/CU.
__global__ __launch_bounds__(512) void gemm_qkv(const unsigned short* __restrict__ A,
                                                const unsigned short* __restrict__ Bw,
                                                const float* __restrict__ cosT,
                                                const float* __restrict__ sinT,
                                                unsigned short* __restrict__ qrope,
                                                unsigned short* __restrict__ krope,
                                                unsigned short* __restrict__ vt) {
  const int K = 2048;
  __shared__ unsigned short sm[3 * 16384];      // 96 KB
  const int tid = threadIdx.x;
  const int w = tid >> 6, l = tid & 63;
  const int lo = l & 15, hi = l >> 4;
  const int cpx = 24;                           // 192 / 8 XCDs
  const int swz = (blockIdx.x & 7) * cpx + (blockIdx.x >> 3);
  const int bm = swz / 12, bn = swz % 12;       // bm 0..15, bn 0..11
  const int wm = w >> 2, wn = w & 3;            // 2M x 4N waves
  f32x4 acc[8][4] = {};
  const unsigned short* Ab = A + (size_t)(bm * 256) * K;
  const unsigned short* Bb = Bw + (size_t)(bn * 256) * K;
  const int srow = tid >> 2;                    // 0..127
  const int scolz = (((tid & 3) ^ ((tid >> 2) & 3)) * 8);
  const int csw = lo & 3;

  const int nk = K >> 5;                        // 64
  GSTAGEQ(sm, 0, 0);
  GSTAGEQ(sm, 1, 32);
  int cur = 0;
  for (int t = 0; t < nk; ++t) {
    if (t + 1 < nk) asm volatile("s_waitcnt vmcnt(4)" ::: "memory");
    else            asm volatile("s_waitcnt vmcnt(0)" ::: "memory");
    __builtin_amdgcn_s_barrier();
    __builtin_amdgcn_sched_barrier(0);
    const int nb2 = (cur + 2 >= 3) ? cur - 1 : cur + 2;
    if (t + 2 < nk) GSTAGEQ(sm, nb2, (t + 2) * 32);
    const unsigned short* As = sm + cur * 16384;
    const unsigned short* Bs = As + 8192;
    const int kk = (hi ^ csw) * 8;
    short8 a[8], b[4];
#pragma unroll
    for (int i = 0; i < 8; ++i)
      a[i] = *(const short8*)&As[(wm * 128 + i * 16 + lo) * 32 + kk];
#pragma unroll
    for (int j = 0; j < 4; ++j)
      b[j] = *(const short8*)&Bs[(wn * 64 + j * 16 + lo) * 32 + kk];
    __builtin_amdgcn_s_setprio(1);
#pragma unroll
    for (int i = 0; i < 8; ++i)
#pragma unroll
      for (int j = 0; j < 4; ++j)
        acc[i][j] = __builtin_amdgcn_mfma_f32_16x16x32_bf16(a[i], b[j], acc[i][j], 0, 0, 0);
    __builtin_amdgcn_s_setprio(0);
    cur = (cur + 1 >= 3) ? 0 : cur + 1;
  }

  // ---- fused epilogue: each wave owns exactly one head-column (wn) of its bn region ----
  const float SC = 0.18033688011112042f;        // 0.125 * log2(e), folded into Q
  if (bn < 8) {
    const int h = bn * 4 + wn;                  // Q head
#pragma unroll
    for (int i = 0; i < 8; ++i)
#pragma unroll
      for (int r = 0; r < 4; ++r) {
        const int R = bm * 256 + wm * 128 + i * 16 + hi * 4 + r;
        const int b = R >> 11, lpos = R & (L_ - 1);
        const float* cr = cosT + lpos * 64;
        const float* sr = sinT + lpos * 64;
        float q0 = acc[i][0][r], q1 = acc[i][1][r], q2 = acc[i][2][r], q3 = acc[i][3][r];
        unsigned short* dst = qrope + ((size_t)(b * NH + h) * L_ + lpos) * 64;
        dst[lo]      = f2b((q0 * cr[lo]      - q2 * sr[lo])      * SC);
        dst[lo + 16] = f2b((q1 * cr[lo + 16] - q3 * sr[lo + 16]) * SC);
        dst[lo + 32] = f2b((q2 * cr[lo + 32] + q0 * sr[lo + 32]) * SC);
        dst[lo + 48] = f2b((q3 * cr[lo + 48] + q1 * sr[lo + 48]) * SC);
      }
  } else if (bn < 10) {
    const int g = (bn - 8) * 4 + wn;            // K head
#pragma unroll
    for (int i = 0; i < 8; ++i)
#pragma unroll
      for (int r = 0; r < 4; ++r) {
        const int R = bm * 256 + wm * 128 + i * 16 + hi * 4 + r;
        const int b = R >> 11, lpos = R & (L_ - 1);
        const float* cr = cosT + lpos * 64;
        const float* sr = sinT + lpos * 64;
        float q0 = acc[i][0][r], q1 = acc[i][1][r], q2 = acc[i][2][r], q3 = acc[i][3][r];
        unsigned short* dst = krope + ((size_t)(b * NKV + g) * L_ + lpos) * 64;
        dst[lo]      = f2b(q0 * cr[lo]      - q2 * sr[lo]);
        dst[lo + 16] = f2b(q1 * cr[lo + 16] - q3 * sr[lo + 16]);
        dst[lo + 32] = f2b(q2 * cr[lo + 32] + q0 * sr[lo + 32]);
        dst[lo + 48] = f2b(q3 * cr[lo + 48] + q1 * sr[lo + 48]);
      }
  } else {
    const int g = (bn - 10) * 4 + wn;           // V head, transposed store Vt[(b,g,d)][lpos]
#pragma unroll
    for (int i = 0; i < 8; ++i)
#pragma unroll
      for (int r = 0; r < 4; ++r) {
        const int R = bm * 256 + wm * 128 + i * 16 + hi * 4 + r;
        const int b = R >> 11, lpos = R & (L_ - 1);
        unsigned short* dst = vt + ((size_t)(b * NKV + g) * HD) * L_ + lpos;
#pragma unroll
        for (int j = 0; j < 4; ++j)
          dst[(size_t)(j * 16 + lo) * L_] = f2b(acc[i][j][r]);
      }
  }
}

// ---------------- Flash attention (causal, GQA), 32x32x16 swapped-operand ----------------
// (r11 verbatim — known good)
__global__ __launch_bounds__(256) void attn(const unsigned short* __restrict__ Qb,
                                            const unsigned short* __restrict__ Kb,
                                            const unsigned short* __restrict__ Vtb,
                                            unsigned short* __restrict__ AO) {
  __shared__ unsigned short smem[3 * 8192];
  const int h = blockIdx.y, b = blockIdx.z;
  const int g = h >> 2;
  const int tid = threadIdx.x;
  const int w = tid >> 6, l = tid & 63;
  const int q5 = l & 31, hi2 = l >> 5;

  const unsigned short* Qh = Qb + (size_t)(b * NH + h) * L_ * HD;
  const char* Kg = (const char*)(Kb + (size_t)(b * NKV + g) * L_ * HD);
  const char* Vg = (const char*)(Vtb + (size_t)(b * NKV + g) * HD * L_);

  const int r8 = l >> 3;
  const int swz_src = ((l & 7) ^ r8) * 16;
  const int myswz = (q5 & 7) << 4;

  const int koff0 = (w * 16 + r8) * 128 + swz_src;
  const int koff1 = koff0 + 1024;
  const int voff0 = (w * 16 + r8) * 4096 + swz_src;
  const int voff1 = voff0 + 32768;
  const int dA0 = w * 1024;
  const int dA1 = dA0 + 512;

  int cA[4];
#pragma unroll
  for (int sc = 0; sc < 4; ++sc) cA[sc] = (sc * 32 + hi2 * 16) ^ myswz;
  const int rK = q5 * 128;

  short8 av2c;
#pragma unroll
  for (int j = 0; j < 8; ++j) av2c[j] = (q5 == 0) ? (short)0x3F80 : (short)0;

#define STAGE2(BUF)                                            \
  {                                                            \
    unsigned short* Kd = smem + (BUF) * 8192;                  \
    gload16(kgp + koff0, Kd + dA0);                            \
    gload16(kgp + koff1, Kd + dA1);                            \
    gload16(vgp + voff0, Kd + 4096 + dA0);                     \
    gload16(vgp + voff1, Kd + 4096 + dA1);                     \
  }

  for (int pass = 0; pass < 2; ++pass) {
    const int qb = pass ? 15 - blockIdx.x : blockIdx.x;
    const unsigned short* Qp = Qh + (size_t)(qb * 128) * HD;

    short8 bq[4];
#pragma unroll
    for (int sc = 0; sc < 4; ++sc)
      bq[sc] = *(const short8*)(Qp + (w * 32 + q5) * HD + sc * 16 + hi2 * 8);

    f32x16 o0 = {}, o1 = {}, o2 = {};
    const int qg = qb * 128 + w * 32 + q5;

    const char* kgp = Kg;
    const char* vgp = Vg;

    const int nt = 2 * qb + 2;
    STAGE2(0);
    kgp += 8192; vgp += 128;
    int cur = 0;
    for (int kt = 0; kt < nt; ++kt) {
      const int nb = (cur == 2) ? 0 : cur + 1;
      if (kt + 1 < nt) {
        STAGE2(nb);
        kgp += 8192; vgp += 128;
        asm volatile("s_waitcnt vmcnt(4)" ::: "memory");
      } else {
        asm volatile("s_waitcnt vmcnt(0)" ::: "memory");
      }
      __builtin_amdgcn_s_barrier();
      __builtin_amdgcn_sched_barrier(0);

      const char* kb = (const char*)smem + cur * 16384 + rK;
      const bool active = (kt * 64 <= qb * 128 + w * 32 + 31);
      if (active) {
        f32x16 s0 = {}, s1 = {};
        __builtin_amdgcn_s_setprio(1);
#pragma unroll
        for (int sc = 0; sc < 4; ++sc) {
          short8 ak = *(const short8*)(kb + cA[sc]);
          s0 = __builtin_amdgcn_mfma_f32_32x32x16_bf16(ak, bq[sc], s0, 0, 0, 0);
        }
#pragma unroll
        for (int sc = 0; sc < 4; ++sc) {
          short8 ak = *(const short8*)(kb + 4096 + cA[sc]);
          s1 = __builtin_amdgcn_mfma_f32_32x32x16_bf16(ak, bq[sc], s1, 0, 0, 0);
        }
        __builtin_amdgcn_s_setprio(0);
        if (kt >= 2 * qb) {
#pragma unroll
          for (int r = 0; r < 16; ++r) {
            const int krow = (r & 3) + 8 * (r >> 2) + 4 * hi2;
            if (kt * 64 + krow > qg)      s0[r] = -1e30f;
            if (kt * 64 + 32 + krow > qg) s1[r] = -1e30f;
          }
        }
#pragma unroll
        for (int r = 0; r < 16; ++r) s0[r] = fexp2(s0[r]);
#pragma unroll
        for (int r = 0; r < 16; ++r) s1[r] = fexp2(s1[r]);
        unsigned int pa[4][4];
#define PACK8(S, Bq, OUT)                                        \
        {                                                        \
          unsigned int u0 = cvtpk_bf16(S[Bq + 0], S[Bq + 1]);    \
          unsigned int u1 = cvtpk_bf16(S[Bq + 2], S[Bq + 3]);    \
          unsigned int u2 = cvtpk_bf16(S[Bq + 4], S[Bq + 5]);    \
          unsigned int u3 = cvtpk_bf16(S[Bq + 6], S[Bq + 7]);    \
          pl32swap(u0, u2); pl32swap(u1, u3);                    \
          OUT[0] = u0; OUT[1] = u1; OUT[2] = u2; OUT[3] = u3;    \
        }
        PACK8(s0, 0, pa[0]); PACK8(s0, 8, pa[1]);
        PACK8(s1, 0, pa[2]); PACK8(s1, 8, pa[3]);
#undef PACK8
        __builtin_amdgcn_s_setprio(1);
#pragma unroll
        for (int kc = 0; kc < 4; ++kc) {
          U8 p; p.u[0] = pa[kc][0]; p.u[1] = pa[kc][1]; p.u[2] = pa[kc][2]; p.u[3] = pa[kc][3];
          short8 av0 = *(const short8*)(kb + 8192 + cA[kc]);
          o0 = __builtin_amdgcn_mfma_f32_32x32x16_bf16(av0, p.s, o0, 0, 0, 0);
          short8 av1 = *(const short8*)(kb + 12288 + cA[kc]);
          o1 = __builtin_amdgcn_mfma_f32_32x32x16_bf16(av1, p.s, o1, 0, 0, 0);
          o2 = __builtin_amdgcn_mfma_f32_32x32x16_bf16(av2c, p.s, o2, 0, 0, 0);
        }
        __builtin_amdgcn_s_setprio(0);
      }
      cur = nb;
    }

    __builtin_amdgcn_s_barrier();

    const float ls = o2[0] + __shfl_xor(o2[0], 32);
    const float inv = 1.f / ls;
    o0 *= inv;
    o1 *= inv;
    const int qrow = w * 32 + q5;
#pragma unroll
    for (int df = 0; df < 2; ++df) {
      const f32x16& o = df ? o1 : o0;
#pragma unroll
      for (int gq = 0; gq < 4; ++gq) {
        unsigned int ulo = cvtpk_bf16(o[4 * gq + 0], o[4 * gq + 1]);
        unsigned int uhi = cvtpk_bf16(o[4 * gq + 2], o[4 * gq + 3]);
        const int colb = df * 64 + gq * 16 + hi2 * 8;
        *(unsigned long long*)((char*)smem + qrow * 128 + (colb ^ myswz)) =
            ((unsigned long long)uhi << 32) | (unsigned long long)ulo;
      }
    }
    __syncthreads();
#pragma unroll
    for (int it = 0; it < 4; ++it) {
      const int row = it * 32 + (tid >> 3);
      const int colb = (tid & 7) * 16;
      short8 v = *(const short8*)((const char*)smem + row * 128 + (colb ^ ((row & 7) << 4)));
      *(short8*)((char*)AO + ((size_t)(b * L_ + qb * 128 + row) * 2048 + h * 64) * 2 + colb) = v;
    }
    __syncthreads();
  }
#undef STAGE2
}

extern "C" void kernel_launch(void* const* d_in, const int* in_sizes, int n_in,
                              void* d_out, int out_size, void* d_ws, size_t ws_size,
                              hipStream_t stream) {
  const float* x    = (const float*)d_in[0];
  const float* cosT = (const float*)d_in[1];
  const float* sinT = (const float*)d_in[2];
  const float* Wq   = (const float*)d_in[3];
  const float* Wk   = (const float*)d_in[4];
  const float* Wv   = (const float*)d_in[5];
  const float* Wo   = (const float*)d_in[6];
  float* out = (float*)d_out;

  char* ws = (char*)d_ws;
  unsigned short* xb    = (unsigned short*)ws;        // 8,388,608 el
  unsigned short* wqkv  = xb + 8388608;               // 6,291,456 el (Wq | Wk | Wv)
  unsigned short* wo    = wqkv + 6291456;             // 4,194,304 el
  unsigned short* qrope = wo + 4194304;               // 8,388,608 el  (B,NH,L,64) roped*SC
  unsigned short* krope = qrope + 8388608;            // 2,097,152 el  (B,NKV,L,64) roped
  unsigned short* vt    = krope + 2097152;            // 2,097,152 el  (B,NKV,64,L)
  unsigned short* ao    = vt + 2097152;               // 8,388,608 el  (B,L,2048)

  conv_all<<<18432, 256, 0, stream>>>(x, Wq, Wk, Wv, Wo, xb, wqkv, wo);

  gemm_qkv<<<192, 512, 0, stream>>>(xb, wqkv, cosT, sinT, qrope, krope, vt);

  attn<<<dim3(8, 32, 2), 256, 0, stream>>>(qrope, krope, vt, ao);

  gemm_bt<<<512, 256, 0, stream>>>(ao, wo, out, 4096, 2048, 2048);
}